// Round 1
// baseline (148.139 us; speedup 1.0000x reference)
//
#include <hip/hip_runtime.h>
#include <hip/hip_bf16.h>
#include <math.h>

#define DIM 256

typedef __bf16 bf16x8 __attribute__((ext_vector_type(8)));
typedef float f32x4 __attribute__((ext_vector_type(4)));

__constant__ const float kTempInvLog2e = 20.0f * 1.4426950408889634f; // (1/temp)*log2(e)
#define LN2 0.6931471805599453f
#define EPS_NORM 1e-8f

// round-to-nearest-even f32 -> bf16 bits
static __device__ inline unsigned short f2bf(float f) {
    unsigned u = __builtin_bit_cast(unsigned, f);
    unsigned r = (u + 0x7fffu + ((u >> 16) & 1u)) >> 16;
    return (unsigned short)r;
}

// Kernel 1: per-row L2 normalize, scale folded into A, emit bf16.
// grid = 2n blocks of 64 threads (one wave per row). Row < n -> A, else B.
__global__ __launch_bounds__(64) void normalize_kernel(
    const float* __restrict__ A, const float* __restrict__ B,
    unsigned short* __restrict__ Abf, unsigned short* __restrict__ Bbf, int n)
{
    int row = blockIdx.x;
    bool isB = row >= n;
    int r = isB ? row - n : row;
    const float* src = (isB ? B : A) + (size_t)r * DIM;
    unsigned short* dst = (isB ? Bbf : Abf) + (size_t)r * DIM;
    int lane = threadIdx.x;

    float4 v = ((const float4*)src)[lane];
    float ss = v.x * v.x + v.y * v.y + v.z * v.z + v.w * v.w;
#pragma unroll
    for (int m = 1; m < 64; m <<= 1) ss += __shfl_xor(ss, m, 64);
    float norm = fmaxf(sqrtf(ss), EPS_NORM);
    float scale = (isB ? 1.0f : kTempInvLog2e) / norm;

    ushort4 o;
    o.x = f2bf(v.x * scale);
    o.y = f2bf(v.y * scale);
    o.z = f2bf(v.z * scale);
    o.w = f2bf(v.w * scale);
    ((ushort4*)dst)[lane] = o;
}

// Kernel 2: fused GEMM (bf16 MFMA 16x16x32) + exp2 + per-row partial sums.
// Block = 256 thr (4 waves). Block covers 64 rows x (n/4) cols.
// Wave w owns the 16-col slice [w*16, w*16+16) of each 64-col tile.
// A fragments (64 rows x 256 K) persist in registers: 4 Mtiles x 8 Ksteps x 4 VGPR = 128 VGPRs.
// B fragments streamed from global (B is 4 MB -> L2 resident).
// Outputs: partial[(split*4+w)*n + row] = sum over this wave's cols of 2^y,
//          diag[row] = y_row,row (log2-scaled logit), written by the matching lane.
__global__ __launch_bounds__(256, 2) void gemm_lse_kernel(
    const unsigned short* __restrict__ Abf, const unsigned short* __restrict__ Bbf,
    float* __restrict__ partial, float* __restrict__ diag, int n)
{
    const int lane = threadIdx.x & 63;
    const int w = threadIdx.x >> 6;
    const int c = lane & 15;   // M index (A), N index (B), col index (C/D)
    const int q = lane >> 4;   // K-chunk index (A,B); row-quad (C/D)
    const int rowbase = blockIdx.x * 64;
    const int ncols = n >> 2;                 // cols per split
    const int colstart = blockIdx.y * ncols;

    // persistent A fragments
    bf16x8 afrag[4][8];
#pragma unroll
    for (int t = 0; t < 4; ++t) {
        const unsigned short* ap = Abf + (size_t)(rowbase + t * 16 + c) * DIM + q * 8;
#pragma unroll
        for (int k = 0; k < 8; ++k)
            afrag[t][k] = *(const bf16x8*)(ap + k * 32);
    }

    float sums[16];
#pragma unroll
    for (int i = 0; i < 16; ++i) sums[i] = 0.0f;

    const unsigned short* bp = Bbf + (size_t)(colstart + w * 16 + c) * DIM + q * 8;
    const int niter = ncols / 64;

    for (int it = 0; it < niter; ++it) {
        bf16x8 bfrag[8];
#pragma unroll
        for (int k = 0; k < 8; ++k)
            bfrag[k] = *(const bf16x8*)(bp + k * 32);
        bp += 64 * DIM;

        f32x4 acc[4];
#pragma unroll
        for (int t = 0; t < 4; ++t) acc[t] = (f32x4){0.f, 0.f, 0.f, 0.f};

#pragma unroll
        for (int k = 0; k < 8; ++k) {
#pragma unroll
            for (int t = 0; t < 4; ++t)
                acc[t] = __builtin_amdgcn_mfma_f32_16x16x32_bf16(
                    afrag[t][k], bfrag[k], acc[t], 0, 0, 0);
        }

        const int gcol = colstart + it * 64 + w * 16 + c;
#pragma unroll
        for (int t = 0; t < 4; ++t) {
#pragma unroll
            for (int r = 0; r < 4; ++r) {
                float y = acc[t][r];
                int grow = rowbase + t * 16 + q * 4 + r;
                if (grow == gcol) diag[grow] = y;   // rare predicated store
                sums[t * 4 + r] += exp2f(y);
            }
        }
    }

    // reduce each row sum across the 16 lanes of its q-group (cols mod 16)
#pragma unroll
    for (int i = 0; i < 16; ++i) {
        float s = sums[i];
        s += __shfl_xor(s, 1, 64);
        s += __shfl_xor(s, 2, 64);
        s += __shfl_xor(s, 4, 64);
        s += __shfl_xor(s, 8, 64);
        sums[i] = s;
    }
    if (c == 0) {
        float* pout = partial + (size_t)(blockIdx.y * 4 + w) * n;
#pragma unroll
        for (int t = 0; t < 4; ++t)
#pragma unroll
            for (int r = 0; r < 4; ++r)
                pout[rowbase + t * 16 + q * 4 + r] = sums[t * 4 + r];
    }
}

// Kernel 3: loss = (ln2/n) * sum_i( log2(sum_p partial[p][i]) - diag[i] )
__global__ __launch_bounds__(256) void reduce_kernel(
    const float* __restrict__ partial, const float* __restrict__ diag,
    float* __restrict__ out, int n)
{
    __shared__ float red[256];
    float local = 0.0f;
    for (int row = threadIdx.x; row < n; row += 256) {
        float s = 0.0f;
#pragma unroll
        for (int p = 0; p < 16; ++p) s += partial[(size_t)p * n + row];
        local += log2f(s) - diag[row];
    }
    red[threadIdx.x] = local;
    __syncthreads();
    for (int off = 128; off > 0; off >>= 1) {
        if (threadIdx.x < off) red[threadIdx.x] += red[threadIdx.x + off];
        __syncthreads();
    }
    if (threadIdx.x == 0) out[0] = red[0] * (LN2 / (float)n);
}

extern "C" void kernel_launch(void* const* d_in, const int* in_sizes, int n_in,
                              void* d_out, int out_size, void* d_ws, size_t ws_size,
                              hipStream_t stream) {
    const int n = in_sizes[0] / DIM;  // 8192
    const float* A = (const float*)d_in[0];
    const float* B = (const float*)d_in[1];
    float* out = (float*)d_out;

    // workspace layout
    unsigned short* Abf = (unsigned short*)d_ws;                 // n*DIM bf16
    unsigned short* Bbf = Abf + (size_t)n * DIM;                 // n*DIM bf16
    float* partial = (float*)(Bbf + (size_t)n * DIM);            // 16*n f32
    float* diag = partial + (size_t)16 * n;                      // n f32

    normalize_kernel<<<2 * n, 64, 0, stream>>>(A, B, Abf, Bbf, n);

    dim3 grid(n / 64, 4);
    gemm_lse_kernel<<<grid, 256, 0, stream>>>(Abf, Bbf, partial, diag, n);

    reduce_kernel<<<1, 256, 0, stream>>>(partial, diag, out, n);
}